// Round 15
// baseline (187.851 us; speedup 1.0000x reference)
//
#include <hip/hip_runtime.h>
#include <cstdint>
#include <cstddef>

// ---------------------------------------------------------------------------
// MHA block: out = proj( causal_softmax( (xWq)(xWk)^T / 8 ) (xWv) )
// B=4, T=2048, C=1024, H=16, D=64.  All GEMM-shaped compute on bf16 MFMA.
// ---------------------------------------------------------------------------

typedef short bf16x8 __attribute__((ext_vector_type(8)));
typedef float f32x4 __attribute__((ext_vector_type(4)));

#define MFMA32(a, b, c) __builtin_amdgcn_mfma_f32_16x16x32_bf16((a), (b), (c), 0, 0, 0)

__device__ __forceinline__ unsigned short f2b(float f) {
  unsigned int x = __builtin_bit_cast(unsigned int, f);
  x += 0x7fffu + ((x >> 16) & 1u);
  return (unsigned short)(x >> 16);
}

__device__ __forceinline__ unsigned int pack2(float a, float b) {
  return (unsigned int)f2b(a) | ((unsigned int)f2b(b) << 16);
}

__device__ __forceinline__ unsigned int cvtpk(float a, float b) {
  unsigned int r;
  asm("v_cvt_pk_bf16_f32 %0, %1, %2" : "=v"(r) : "v"(a), "v"(b));
  return r;
}

__device__ __forceinline__ float exp2v(float x) {
  float r;
  asm("v_exp_f32 %0, %1" : "=v"(r) : "v"(x));
  return r;
}

__device__ __forceinline__ void gload16(const void* g, void* l) {
  __builtin_amdgcn_global_load_lds(
      (const __attribute__((address_space(1))) void*)g,
      (__attribute__((address_space(3))) void*)l, 16, 0, 0);
}

// ---------------------------------------------------------------------------
__global__ __launch_bounds__(256) void k_conv_x(const float* __restrict__ in,
                                                unsigned short* __restrict__ out, int n4) {
  int i = blockIdx.x * 256 + threadIdx.x;
  if (i >= n4) return;
  float4 v = reinterpret_cast<const float4*>(in)[i];
  ushort4 o;
  o.x = f2b(v.x); o.y = f2b(v.y); o.z = f2b(v.z); o.w = f2b(v.w);
  reinterpret_cast<ushort4*>(out)[i] = o;
}

// ---------------------------------------------------------------------------
__global__ __launch_bounds__(256) void k_transpose(const float* __restrict__ in,
                                                   unsigned short* __restrict__ out,
                                                   int R, int C) {
  __shared__ float tile[32][33];
  int c0 = blockIdx.x * 32, r0 = blockIdx.y * 32;
  int tx = threadIdx.x & 31, ty = threadIdx.x >> 5;
#pragma unroll
  for (int j = 0; j < 4; ++j)
    tile[ty + 8 * j][tx] = in[(size_t)(r0 + ty + 8 * j) * C + c0 + tx];
  __syncthreads();
#pragma unroll
  for (int j = 0; j < 4; ++j)
    out[(size_t)(c0 + ty + 8 * j) * R + r0 + tx] = f2b(tile[tx][ty + 8 * j]);
}

// ---------------------------------------------------------------------------
// bf16 GEMM, 128x128 tile, 4 waves, 64x64/wave.
// NEW (R15): BK=32 DOUBLE-BUFFERED pipeline (the attn-proven pattern):
//   stage kt+1 issued BEFORE computing kt, counted vmcnt(4), raw s_barrier
//   pairs — removes the per-K-tile full drain (the m97 stall) while keeping
//   32KB LDS (same 4 blocks/CU occupancy).  64B rows -> swizzle
//   chunk ^= (row>>1)&3 (pre-swizzled source; 2-way residual = free).
// EPI=0: LDS-bounce epilogue -> q/k/v ws.  EPI=1: direct f32 out.
// ---------------------------------------------------------------------------
template <int EPI>
__global__ __launch_bounds__(256) void k_gemm(const unsigned short* __restrict__ A,
                                              const unsigned short* __restrict__ Bt,
                                              float* __restrict__ outF,
                                              unsigned short* __restrict__ q_ws,
                                              unsigned short* __restrict__ k_ws,
                                              unsigned short* __restrict__ v_ws,
                                              int M, int N) {
  constexpr int K = 1024;
  __shared__ unsigned short smem[16384];  // A dbuf (16KB) | B dbuf (16KB); epi reuses
  const int bn = blockIdx.x, bm = blockIdx.y;
  const int tid = threadIdx.x;
  const int w = tid >> 6, lane = tid & 63;
  const int wm = w >> 1, wn = w & 1;
  const int c = lane & 15, g = lane >> 4;
  const int cs = g ^ ((c >> 1) & 3);  // read-side swizzled chunk (16B units)

  f32x4 acc[4][4];
#pragma unroll
  for (int i = 0; i < 4; ++i)
#pragma unroll
    for (int j = 0; j < 4; ++j) acc[i][j] = (f32x4){0.f, 0.f, 0.f, 0.f};

  // staging: instr i covers 16 rows; lane: row_local = lane>>2, chunk = lane&3;
  // source chunk pre-swizzled so LDS[row][j] = src[row][j ^ ((row>>1)&3)]
  const int srow = 32 * w + (lane >> 2);
  const int scol = 8 * ((lane & 3) ^ ((lane >> 3) & 3));
  const unsigned short* Ag = A + (size_t)(bm * 128 + srow) * K + scol;
  const unsigned short* Bg = Bt + (size_t)(bn * 128 + srow) * K + scol;
  char* Asm = (char*)smem;            // [2][8KB]
  char* Bsm = (char*)smem + 16384;    // [2][8KB]

#define STG(kt, b)                                                             \
  {                                                                            \
    gload16(Ag + (kt) * 32, Asm + (b) * 8192 + w * 2048);                      \
    gload16(Ag + (size_t)16 * K + (kt) * 32, Asm + (b) * 8192 + w * 2048 + 1024); \
    gload16(Bg + (kt) * 32, Bsm + (b) * 8192 + w * 2048);                      \
    gload16(Bg + (size_t)16 * K + (kt) * 32, Bsm + (b) * 8192 + w * 2048 + 1024); \
  }

  STG(0, 0)
#pragma unroll 1
  for (int kt = 0; kt < 32; ++kt) {
    const int cur = kt & 1;
    if (kt + 1 < 32) {
      STG(kt + 1, cur ^ 1)
      asm volatile("s_waitcnt vmcnt(4)" ::: "memory");  // STG(kt) landed
    } else {
      asm volatile("s_waitcnt vmcnt(0)" ::: "memory");
    }
    __builtin_amdgcn_s_barrier();  // buf[cur] visible to all waves
    bf16x8 af[4], bfr[4];
#pragma unroll
    for (int mf = 0; mf < 4; ++mf)
      af[mf] = *(const bf16x8*)(Asm + cur * 8192 + (wm * 64 + mf * 16 + c) * 64 + cs * 16);
#pragma unroll
    for (int nf = 0; nf < 4; ++nf)
      bfr[nf] = *(const bf16x8*)(Bsm + cur * 8192 + (wn * 64 + nf * 16 + c) * 64 + cs * 16);
    __builtin_amdgcn_s_setprio(1);
#pragma unroll
    for (int mf = 0; mf < 4; ++mf)
#pragma unroll
      for (int nf = 0; nf < 4; ++nf)
        acc[mf][nf] = MFMA32(af[mf], bfr[nf], acc[mf][nf]);
    __builtin_amdgcn_s_setprio(0);
    __builtin_amdgcn_s_barrier();  // readers done before next stage overwrites
  }
#undef STG

  const int rowb = bm * 128 + wm * 64;
  const int colb = bn * 128 + wn * 64;
  if (EPI == 1) {
#pragma unroll
    for (int mf = 0; mf < 4; ++mf)
#pragma unroll
      for (int nf = 0; nf < 4; ++nf)
#pragma unroll
        for (int r = 0; r < 4; ++r) {
          int row = rowb + mf * 16 + 4 * g + r;
          int col = colb + nf * 16 + c;
          outF[(size_t)row * N + col] = acc[mf][nf][r];
        }
  } else {
    const int sec = colb >> 10;
    const int hh = (colb & 1023) >> 6;
    const int b = rowb >> 11, t0 = rowb & 2047;
    unsigned short* Lw = smem + w * 4096;

    __syncthreads();
    if (sec < 2) {
      const float sc = (sec == 0) ? 0.125f * 1.4426950408889634f : 1.f;
#pragma unroll
      for (int mf = 0; mf < 4; ++mf)
#pragma unroll
        for (int nf = 0; nf < 4; ++nf)
#pragma unroll
          for (int r = 0; r < 4; ++r)
            Lw[(16 * mf + 4 * g + r) * 64 + 16 * nf + c] = f2b(acc[mf][nf][r] * sc);
    } else {
#pragma unroll
      for (int mf = 0; mf < 4; ++mf)
#pragma unroll
        for (int nf = 0; nf < 4; ++nf)
#pragma unroll
          for (int rr = 0; rr < 2; ++rr)
            *(unsigned int*)&Lw[(16 * nf + c) * 64 + 16 * mf + 4 * g + 2 * rr] =
                pack2(acc[mf][nf][2 * rr], acc[mf][nf][2 * rr + 1]);
    }
    asm volatile("s_waitcnt lgkmcnt(0)" ::: "memory");
    const int rw = lane >> 3, ch = lane & 7;
    const int chx = ch ^ rw;
    if (sec == 0) {
      unsigned short* dst = q_ws + ((size_t)(b * 16 + hh) * 2048 + t0) * 64;
#pragma unroll
      for (int i = 0; i < 8; ++i) {
        int tl = i * 8 + rw;
        *(bf16x8*)(dst + (size_t)tl * 64 + ch * 8) = *(const bf16x8*)&Lw[tl * 64 + ch * 8];
      }
    } else if (sec == 1) {
      unsigned short* dst = k_ws + ((size_t)(b * 16 + hh) * 2048 + t0) * 64;
#pragma unroll
      for (int i = 0; i < 8; ++i) {
        int tl = i * 8 + rw;
        *(bf16x8*)(dst + (size_t)tl * 64 + chx * 8) = *(const bf16x8*)&Lw[tl * 64 + ch * 8];
      }
    } else {
      unsigned short* dst = v_ws + (size_t)(b * 16 + hh) * 64 * 2048 + t0;
#pragma unroll
      for (int i = 0; i < 8; ++i) {
        int dl = i * 8 + rw;
        *(bf16x8*)(dst + (size_t)dl * 2048 + chx * 8) = *(const bf16x8*)&Lw[dl * 64 + ch * 8];
      }
    }
  }
}

// ---------------------------------------------------------------------------
// Flash attention, causal. 512 blocks x 512 threads (8 waves).  Exact R14
// version (best measured ~78.5us): R9 structure + V-frag hoist before softmax.
// ---------------------------------------------------------------------------
__global__ __launch_bounds__(512) void k_attn(const unsigned short* __restrict__ q_ws,
                                              const unsigned short* __restrict__ k_ws,
                                              const unsigned short* __restrict__ v_ws,
                                              unsigned short* __restrict__ y_ws) {
  constexpr int T = 2048;
  __shared__ unsigned short Ks[2][64 * 64];
  __shared__ unsigned short Vs[2][64 * 64];
  const int f = blockIdx.x;
  const int f2 = (f & 7) * 64 + (f >> 3);
  const int bh = f2 >> 3;
  const int xi = f2 & 7;
  const int tid = threadIdx.x, w = tid >> 6, lane = tid & 63;
  const int c = lane & 15, g = lane >> 4;
  const int cl = c & 7;
  const size_t base = (size_t)bh * T * 64;
  const unsigned short* Kb = k_ws + base;
  const unsigned short* Vb = v_ws + base;
  const unsigned short* Qb = q_ws + base;

  const int srow = w * 8 + (lane >> 3);
  const int sch = lane & 7;

#pragma unroll 1
  for (int ph = 0; ph < 2; ++ph) {
    const int q0 = (ph == 0 ? xi : 15 - xi) * 128;
    const int qrow = q0 + 16 * w + c;
    const int q_max_wave = q0 + 16 * w + 15;
    const int n_kt = (q0 >> 6) + 2;
    bf16x8 qf[2];
#pragma unroll
    for (int u = 0; u < 2; ++u)
      qf[u] = *(const bf16x8*)(Qb + (size_t)qrow * 64 + 32 * u + 8 * g);

    f32x4 yacc[4];
#pragma unroll
    for (int i = 0; i < 4; ++i) yacc[i] = (f32x4){0.f, 0.f, 0.f, 0.f};
    float m_run = -1e30f, l_part = 0.f;

    __syncthreads();  // prior phase fully done before restaging buf 0
    gload16(Kb + (size_t)srow * 64 + sch * 8, (char*)&Ks[0][0] + w * 1024);
    gload16(Vb + (size_t)srow * T + sch * 8, (char*)&Vs[0][0] + w * 1024);

#pragma unroll 1
    for (int kt = 0; kt < n_kt; ++kt) {
      const int k0 = kt * 64;
      const int cur = kt & 1;
      if (kt + 1 < n_kt) {
        const int k0n = k0 + 64;
        gload16(Kb + (size_t)(k0n + srow) * 64 + sch * 8, (char*)&Ks[cur ^ 1][0] + w * 1024);
        gload16(Vb + (size_t)srow * T + k0n + sch * 8, (char*)&Vs[cur ^ 1][0] + w * 1024);
        asm volatile("s_waitcnt vmcnt(2)" ::: "memory");
      } else {
        asm volatile("s_waitcnt vmcnt(0)" ::: "memory");
      }
      __builtin_amdgcn_s_barrier();

      if (k0 <= q_max_wave) {
        const char* KsC = (const char*)&Ks[cur][0];
        const char* VsC = (const char*)&Vs[cur][0];
        f32x4 s[4];
        __builtin_amdgcn_s_setprio(1);
#pragma unroll
        for (int tf = 0; tf < 4; ++tf) {
          bf16x8 kf0 = *(const bf16x8*)(KsC + (16 * tf + c) * 128 + (g ^ cl) * 16);
          bf16x8 kf1 = *(const bf16x8*)(KsC + (16 * tf + c) * 128 + ((4 + g) ^ cl) * 16);
          f32x4 z = (f32x4){0.f, 0.f, 0.f, 0.f};
          z = MFMA32(kf0, qf[0], z);
          s[tf] = MFMA32(kf1, qf[1], z);
        }
        __builtin_amdgcn_s_setprio(0);
        // V-frag prefetch: LDS latency overlaps the softmax VALU below
        bf16x8 vf[2][4];
#pragma unroll
        for (int h = 0; h < 2; ++h)
#pragma unroll
          for (int df = 0; df < 4; ++df)
            vf[h][df] = *(const bf16x8*)(VsC + (16 * df + c) * 128 + ((h * 4 + g) ^ cl) * 16);
        if (k0 + 63 > q0 + 16 * w) {
#pragma unroll
          for (int tf = 0; tf < 4; ++tf)
#pragma unroll
            for (int r = 0; r < 4; ++r)
              if (k0 + 16 * tf + 4 * g + r > qrow) s[tf][r] = -1e30f;
        }
        float mx0 = fmaxf(fmaxf(s[0][0], s[0][1]), fmaxf(s[0][2], s[0][3]));
        float mx1 = fmaxf(fmaxf(s[1][0], s[1][1]), fmaxf(s[1][2], s[1][3]));
        float mx2 = fmaxf(fmaxf(s[2][0], s[2][1]), fmaxf(s[2][2], s[2][3]));
        float mx3 = fmaxf(fmaxf(s[3][0], s[3][1]), fmaxf(s[3][2], s[3][3]));
        float mx = fmaxf(fmaxf(mx0, mx1), fmaxf(mx2, mx3));
        mx = fmaxf(mx, __shfl_xor(mx, 16));
        mx = fmaxf(mx, __shfl_xor(mx, 32));
        if (__any(mx > m_run + 11.5f)) {
          float m_new = fmaxf(m_run, mx);
          float corr = exp2v(m_run - m_new);
          l_part *= corr;
#pragma unroll
          for (int i = 0; i < 4; ++i) yacc[i] *= corr;
          m_run = m_new;
        }
        float p[16];
#pragma unroll
        for (int tf = 0; tf < 4; ++tf)
#pragma unroll
          for (int r = 0; r < 4; ++r) p[tf * 4 + r] = exp2v(s[tf][r] - m_run);
        float ps = ((p[0] + p[1]) + (p[2] + p[3])) + ((p[4] + p[5]) + (p[6] + p[7]));
        ps += ((p[8] + p[9]) + (p[10] + p[11])) + ((p[12] + p[13]) + (p[14] + p[15]));
        l_part += ps;

#pragma unroll
        for (int h = 0; h < 2; ++h) {
          unsigned int lo0 = cvtpk(p[8 * h + 0], p[8 * h + 1]);
          unsigned int hi0 = cvtpk(p[8 * h + 2], p[8 * h + 3]);
          unsigned int lo1 = cvtpk(p[8 * h + 4], p[8 * h + 5]);
          unsigned int hi1 = cvtpk(p[8 * h + 6], p[8 * h + 7]);
          int a2 = 2 * (g & 1);
          int srcA = 16 * a2 + c, srcB = srcA + 16;
          unsigned int Al0 = __shfl(lo0, srcA), Ah0 = __shfl(hi0, srcA);
          unsigned int Al1 = __shfl(lo1, srcA), Ah1 = __shfl(hi1, srcA);
          unsigned int Bl0 = __shfl(lo0, srcB), Bh0 = __shfl(hi0, srcB);
          unsigned int Bl1 = __shfl(lo1, srcB), Bh1 = __shfl(hi1, srcB);
          bool f1 = (g >= 2);
          union { unsigned int u[4]; bf16x8 v; } pf;
          pf.u[0] = f1 ? Al1 : Al0;
          pf.u[1] = f1 ? Ah1 : Ah0;
          pf.u[2] = f1 ? Bl1 : Bl0;
          pf.u[3] = f1 ? Bh1 : Bh0;
          __builtin_amdgcn_s_setprio(1);
#pragma unroll
          for (int df = 0; df < 4; ++df)
            yacc[df] = MFMA32(vf[h][df], pf.v, yacc[df]);
          __builtin_amdgcn_s_setprio(0);
        }
      }
      __builtin_amdgcn_s_barrier();
    }

    float lt = l_part;
    lt += __shfl_xor(lt, 16);
    lt += __shfl_xor(lt, 32);
    float inv = 1.f / lt;
    const int b = bh >> 4, hh = bh & 15;
#pragma unroll
    for (int df = 0; df < 4; ++df) {
      uint2 o;
      o.x = cvtpk(yacc[df][0] * inv, yacc[df][1] * inv);
      o.y = cvtpk(yacc[df][2] * inv, yacc[df][3] * inv);
      *(uint2*)(y_ws + (size_t)(b * 2048 + qrow) * 1024 + hh * 64 + 16 * df + 4 * g) = o;
    }
  }
}

// ---------------------------------------------------------------------------
extern "C" void kernel_launch(void* const* d_in, const int* in_sizes, int n_in,
                              void* d_out, int out_size, void* d_ws, size_t ws_size,
                              hipStream_t stream) {
  const float* x = (const float*)d_in[0];      // (4, 2048, 1024)
  const float* Wqkv = (const float*)d_in[1];   // (1024, 3072)
  const float* Wproj = (const float*)d_in[2];  // (1024, 1024)
  float* out = (float*)d_out;                  // (4, 2048, 1024)
  char* ws = (char*)d_ws;

  unsigned short* x_bf = (unsigned short*)(ws);                    // 16 MiB
  unsigned short* wqkvT = (unsigned short*)(ws + 16777216);        // 6 MiB
  unsigned short* wprojT = (unsigned short*)(ws + 23068672);       // 2 MiB
  unsigned short* q_ws = (unsigned short*)(ws + 25165824);         // 16 MiB
  unsigned short* k_ws = (unsigned short*)(ws + 41943040);         // 16 MiB
  unsigned short* v_ws = (unsigned short*)(ws + 58720256);         // 16 MiB
  unsigned short* y_ws = (unsigned short*)(ws + 75497472);         // 16 MiB

  k_conv_x<<<8192, 256, 0, stream>>>(x, x_bf, 2097152);
  k_transpose<<<dim3(96, 32), 256, 0, stream>>>(Wqkv, wqkvT, 1024, 3072);
  k_transpose<<<dim3(32, 32), 256, 0, stream>>>(Wproj, wprojT, 1024, 1024);
  k_gemm<0><<<dim3(24, 64), 256, 0, stream>>>(x_bf, wqkvT, nullptr, q_ws, k_ws, v_ws, 8192, 3072);
  k_attn<<<512, 512, 0, stream>>>(q_ws, k_ws, v_ws, y_ws);
  k_gemm<1><<<dim3(8, 64), 256, 0, stream>>>(y_ws, wprojT, out, nullptr, nullptr, nullptr, 8192, 1024);
}

// Round 16
// 183.434 us; speedup vs baseline: 1.0241x; 1.0241x over previous
//
#include <hip/hip_runtime.h>
#include <cstdint>
#include <cstddef>

// ---------------------------------------------------------------------------
// MHA block: out = proj( causal_softmax( (xWq)(xWk)^T / 8 ) (xWv) )
// B=4, T=2048, C=1024, H=16, D=64.  All GEMM-shaped compute on bf16 MFMA.
// ---------------------------------------------------------------------------

typedef short bf16x8 __attribute__((ext_vector_type(8)));
typedef float f32x4 __attribute__((ext_vector_type(4)));
typedef float f32x16 __attribute__((ext_vector_type(16)));

#define MFMA32(a, b, c) __builtin_amdgcn_mfma_f32_16x16x32_bf16((a), (b), (c), 0, 0, 0)
#define MFMA3216(a, b, c) __builtin_amdgcn_mfma_f32_32x32x16_bf16((a), (b), (c), 0, 0, 0)

__device__ __forceinline__ unsigned short f2b(float f) {
  unsigned int x = __builtin_bit_cast(unsigned int, f);
  x += 0x7fffu + ((x >> 16) & 1u);
  return (unsigned short)(x >> 16);
}

__device__ __forceinline__ unsigned int pack2(float a, float b) {
  return (unsigned int)f2b(a) | ((unsigned int)f2b(b) << 16);
}

__device__ __forceinline__ unsigned int cvtpk(float a, float b) {
  unsigned int r;
  asm("v_cvt_pk_bf16_f32 %0, %1, %2" : "=v"(r) : "v"(a), "v"(b));
  return r;
}

__device__ __forceinline__ float exp2v(float x) {
  float r;
  asm("v_exp_f32 %0, %1" : "=v"(r) : "v"(x));
  return r;
}

__device__ __forceinline__ void gload16(const void* g, void* l) {
  __builtin_amdgcn_global_load_lds(
      (const __attribute__((address_space(1))) void*)g,
      (__attribute__((address_space(3))) void*)l, 16, 0, 0);
}

// ---------------------------------------------------------------------------
__global__ __launch_bounds__(256) void k_conv_x(const float* __restrict__ in,
                                                unsigned short* __restrict__ out, int n4) {
  int i = blockIdx.x * 256 + threadIdx.x;
  if (i >= n4) return;
  float4 v = reinterpret_cast<const float4*>(in)[i];
  ushort4 o;
  o.x = f2b(v.x); o.y = f2b(v.y); o.z = f2b(v.z); o.w = f2b(v.w);
  reinterpret_cast<ushort4*>(out)[i] = o;
}

// ---------------------------------------------------------------------------
__global__ __launch_bounds__(256) void k_transpose(const float* __restrict__ in,
                                                   unsigned short* __restrict__ out,
                                                   int R, int C) {
  __shared__ float tile[32][33];
  int c0 = blockIdx.x * 32, r0 = blockIdx.y * 32;
  int tx = threadIdx.x & 31, ty = threadIdx.x >> 5;
#pragma unroll
  for (int j = 0; j < 4; ++j)
    tile[ty + 8 * j][tx] = in[(size_t)(r0 + ty + 8 * j) * C + c0 + tx];
  __syncthreads();
#pragma unroll
  for (int j = 0; j < 4; ++j)
    out[(size_t)(c0 + ty + 8 * j) * R + r0 + tx] = f2b(tile[tx][ty + 8 * j]);
}

// ---------------------------------------------------------------------------
// bf16 GEMM (exact R14: m97 mainloop + both-sides LDS XOR-swizzle, BK=64,
// conflict-free ds_reads, default dispatch order).  128x128 tile, 4 waves.
// EPI=0: LDS-bounce epilogue -> q/k/v ws.  EPI=1: direct f32 out.
// ---------------------------------------------------------------------------
template <int EPI>
__global__ __launch_bounds__(256) void k_gemm(const unsigned short* __restrict__ A,
                                              const unsigned short* __restrict__ Bt,
                                              float* __restrict__ outF,
                                              unsigned short* __restrict__ q_ws,
                                              unsigned short* __restrict__ k_ws,
                                              unsigned short* __restrict__ v_ws,
                                              int M, int N) {
  constexpr int K = 1024;
  __shared__ unsigned short smem[16384];  // As | Bs; epilogue reuses
  unsigned short* As = smem;
  unsigned short* Bs = smem + 8192;
  const int bn = blockIdx.x, bm = blockIdx.y;
  const int tid = threadIdx.x;
  const int w = tid >> 6, lane = tid & 63;
  const int wm = w >> 1, wn = w & 1;
  const int c = lane & 15, g = lane >> 4;
  const int cl8 = c & 7;

  f32x4 acc[4][4];
#pragma unroll
  for (int i = 0; i < 4; ++i)
#pragma unroll
    for (int j = 0; j < 4; ++j) acc[i][j] = (f32x4){0.f, 0.f, 0.f, 0.f};

  const int srow = 32 * w + (lane >> 3);
  const int scol = 8 * ((lane & 7) ^ (lane >> 3));
  const unsigned short* Ag = A + (size_t)(bm * 128 + srow) * K + scol;
  const unsigned short* Bg = Bt + (size_t)(bn * 128 + srow) * K + scol;
  char* AsB = (char*)As + w * 4096;
  char* BsB = (char*)Bs + w * 4096;

  for (int kt = 0; kt < K / 64; ++kt) {
    const int kb = kt * 64;
    __syncthreads();
#pragma unroll
    for (int i = 0; i < 4; ++i) {
      gload16(Ag + (size_t)(8 * i) * K + kb, AsB + i * 1024);
      gload16(Bg + (size_t)(8 * i) * K + kb, BsB + i * 1024);
    }
    asm volatile("s_waitcnt vmcnt(0)" ::: "memory");
    __syncthreads();
#pragma unroll
    for (int u = 0; u < 2; ++u) {
      bf16x8 af[4], bfr[4];
#pragma unroll
      for (int mf = 0; mf < 4; ++mf)
        af[mf] = *(const bf16x8*)((const char*)As + (wm * 64 + mf * 16 + c) * 128 +
                                  (((u * 4 + g) ^ cl8) * 16));
#pragma unroll
      for (int nf = 0; nf < 4; ++nf)
        bfr[nf] = *(const bf16x8*)((const char*)Bs + (wn * 64 + nf * 16 + c) * 128 +
                                   (((u * 4 + g) ^ cl8) * 16));
#pragma unroll
      for (int mf = 0; mf < 4; ++mf)
#pragma unroll
        for (int nf = 0; nf < 4; ++nf)
          acc[mf][nf] = MFMA32(af[mf], bfr[nf], acc[mf][nf]);
    }
  }

  const int rowb = bm * 128 + wm * 64;
  const int colb = bn * 128 + wn * 64;
  if (EPI == 1) {
#pragma unroll
    for (int mf = 0; mf < 4; ++mf)
#pragma unroll
      for (int nf = 0; nf < 4; ++nf)
#pragma unroll
        for (int r = 0; r < 4; ++r) {
          int row = rowb + mf * 16 + 4 * g + r;
          int col = colb + nf * 16 + c;
          outF[(size_t)row * N + col] = acc[mf][nf][r];
        }
  } else {
    const int sec = colb >> 10;
    const int hh = (colb & 1023) >> 6;
    const int b = rowb >> 11, t0 = rowb & 2047;
    unsigned short* Lw = smem + w * 4096;

    __syncthreads();
    if (sec < 2) {
      const float sc = (sec == 0) ? 0.125f * 1.4426950408889634f : 1.f;
#pragma unroll
      for (int mf = 0; mf < 4; ++mf)
#pragma unroll
        for (int nf = 0; nf < 4; ++nf)
#pragma unroll
          for (int r = 0; r < 4; ++r)
            Lw[(16 * mf + 4 * g + r) * 64 + 16 * nf + c] = f2b(acc[mf][nf][r] * sc);
    } else {
#pragma unroll
      for (int mf = 0; mf < 4; ++mf)
#pragma unroll
        for (int nf = 0; nf < 4; ++nf)
#pragma unroll
          for (int rr = 0; rr < 2; ++rr)
            *(unsigned int*)&Lw[(16 * nf + c) * 64 + 16 * mf + 4 * g + 2 * rr] =
                pack2(acc[mf][nf][2 * rr], acc[mf][nf][2 * rr + 1]);
    }
    asm volatile("s_waitcnt lgkmcnt(0)" ::: "memory");
    const int rw = lane >> 3, ch = lane & 7;
    const int chx = ch ^ rw;
    if (sec == 0) {
      unsigned short* dst = q_ws + ((size_t)(b * 16 + hh) * 2048 + t0) * 64;
#pragma unroll
      for (int i = 0; i < 8; ++i) {
        int tl = i * 8 + rw;
        *(bf16x8*)(dst + (size_t)tl * 64 + ch * 8) = *(const bf16x8*)&Lw[tl * 64 + ch * 8];
      }
    } else if (sec == 1) {
      unsigned short* dst = k_ws + ((size_t)(b * 16 + hh) * 2048 + t0) * 64;
#pragma unroll
      for (int i = 0; i < 8; ++i) {
        int tl = i * 8 + rw;
        *(bf16x8*)(dst + (size_t)tl * 64 + chx * 8) = *(const bf16x8*)&Lw[tl * 64 + ch * 8];
      }
    } else {
      unsigned short* dst = v_ws + (size_t)(b * 16 + hh) * 64 * 2048 + t0;
#pragma unroll
      for (int i = 0; i < 8; ++i) {
        int dl = i * 8 + rw;
        *(bf16x8*)(dst + (size_t)dl * 2048 + chx * 8) = *(const bf16x8*)&Lw[dl * 64 + ch * 8];
      }
    }
  }
}

// ---------------------------------------------------------------------------
// Flash attention, causal.  NEW (R16): 32x32x16 MFMA structure (m214-style).
// 512 blocks x 256 threads (4 waves), 4 blocks/CU = 16 waves/CU.
// Wave owns 32 q-rows (col = lane&31); each lane owns a FULL q-column:
//  - softmax is lane-local + one shfl_xor(32) combine (no 16-lane reduce)
//  - K/V fragment reads serve 2x rows -> per-row LDS traffic halved
//  - P->B-operand regroup: 8 shuffles/kt (vs 16), via C/D map
//    row=(reg&3)+8*(reg>>2)+4*(lane>>5), B map k=8*(lane>>5)+j.
// KVBLK=64 double-buffered, counted vmcnt(4), raw s_barrier (R10 staging).
// ---------------------------------------------------------------------------
__global__ __launch_bounds__(256, 4) void k_attn(const unsigned short* __restrict__ q_ws,
                                                 const unsigned short* __restrict__ k_ws,
                                                 const unsigned short* __restrict__ v_ws,
                                                 unsigned short* __restrict__ y_ws) {
  constexpr int T = 2048;
  __shared__ unsigned short Ks[2][64 * 64];
  __shared__ unsigned short Vs[2][64 * 64];
  const int f = blockIdx.x;
  const int f2 = (f & 7) * 64 + (f >> 3);
  const int bh = f2 >> 3;
  const int xi = f2 & 7;
  const int tid = threadIdx.x, w = tid >> 6, lane = tid & 63;
  const int q32 = lane & 31;  // q-col within wave tile; also K/V row index
  const int hi = lane >> 5;
  const int l7 = lane & 7;
  const size_t base = (size_t)bh * T * 64;
  const unsigned short* Kb = k_ws + base;
  const unsigned short* Vb = v_ws + base;
  const unsigned short* Qb = q_ws + base;

  const int srow = w * 16 + (lane >> 3);  // staging rows (2 instrs x 8 rows)
  const int sch = lane & 7;

#pragma unroll 1
  for (int ph = 0; ph < 2; ++ph) {
    const int q0 = (ph == 0 ? xi : 15 - xi) * 128;
    const int qb = q0 + 32 * w;
    const int qcol = qb + q32;
    const int n_kt = (q0 >> 6) + 2;
    bf16x8 qf[4];
#pragma unroll
    for (int ks = 0; ks < 4; ++ks)
      qf[ks] = *(const bf16x8*)(Qb + (size_t)qcol * 64 + 16 * ks + 8 * hi);

    f32x16 yacc[2];
#pragma unroll
    for (int db = 0; db < 2; ++db)
#pragma unroll
      for (int i = 0; i < 16; ++i) yacc[db][i] = 0.f;
    float m_run = -1e30f, l_part = 0.f;

    __syncthreads();  // prior phase fully done (drains all) before restaging
    gload16(Kb + (size_t)srow * 64 + sch * 8, (char*)&Ks[0][0] + w * 2048);
    gload16(Kb + (size_t)(srow + 8) * 64 + sch * 8, (char*)&Ks[0][0] + w * 2048 + 1024);
    gload16(Vb + (size_t)srow * T + sch * 8, (char*)&Vs[0][0] + w * 2048);
    gload16(Vb + (size_t)(srow + 8) * T + sch * 8, (char*)&Vs[0][0] + w * 2048 + 1024);

#pragma unroll 1
    for (int kt = 0; kt < n_kt; ++kt) {
      const int k0 = kt * 64;
      const int cur = kt & 1;
      if (kt + 1 < n_kt) {
        const int k0n = k0 + 64;
        char* KsW = (char*)&Ks[cur ^ 1][0] + w * 2048;
        char* VsW = (char*)&Vs[cur ^ 1][0] + w * 2048;
        gload16(Kb + (size_t)(k0n + srow) * 64 + sch * 8, KsW);
        gload16(Kb + (size_t)(k0n + srow + 8) * 64 + sch * 8, KsW + 1024);
        gload16(Vb + (size_t)srow * T + k0n + sch * 8, VsW);
        gload16(Vb + (size_t)(srow + 8) * T + k0n + sch * 8, VsW + 1024);
        asm volatile("s_waitcnt vmcnt(4)" ::: "memory");
      } else {
        asm volatile("s_waitcnt vmcnt(0)" ::: "memory");
      }
      __builtin_amdgcn_s_barrier();

      if (k0 <= qb + 31) {  // wave-uniform include (k0 <= qb always then)
        const char* KsC = (const char*)&Ks[cur][0];
        const char* VsC = (const char*)&Vs[cur][0];
        // QK^T: S^T[tk][q] per 32-row tk-block, 4 k-steps of 16 over D=64
        f32x16 s[2];
#pragma unroll
        for (int tb = 0; tb < 2; ++tb)
#pragma unroll
          for (int i = 0; i < 16; ++i) s[tb][i] = 0.f;
        __builtin_amdgcn_s_setprio(1);
#pragma unroll
        for (int ks = 0; ks < 4; ++ks) {
          const int chk = ((2 * ks + hi) ^ l7) * 16;
#pragma unroll
          for (int tb = 0; tb < 2; ++tb) {
            const int row = 32 * tb + q32;
            bf16x8 kf = *(const bf16x8*)(KsC + row * 128 + chk);
            s[tb] = MFMA3216(kf, qf[ks], s[tb]);
          }
        }
        __builtin_amdgcn_s_setprio(0);
        // causal mask (diagonal tiles only): tk = k0+32tb+(r&3)+8*(r>>2)+4hi
        if (k0 + 63 > qb) {
#pragma unroll
          for (int tb = 0; tb < 2; ++tb)
#pragma unroll
            for (int r = 0; r < 16; ++r) {
              int tk = k0 + 32 * tb + (r & 3) + 8 * (r >> 2) + 4 * hi;
              if (tk > qcol) s[tb][r] = -1e30f;
            }
        }
        // lane-local max over own 32 rows + cross-half combine
        float mx = s[0][0];
#pragma unroll
        for (int tb = 0; tb < 2; ++tb)
#pragma unroll
          for (int r = 0; r < 16; ++r) mx = fmaxf(mx, s[tb][r]);
        mx = fmaxf(mx, __shfl_xor(mx, 32));
        if (__any(mx > m_run + 11.5f)) {
          float m_new = fmaxf(m_run, mx);
          float corr = exp2v(m_run - m_new);
          l_part *= corr;
#pragma unroll
          for (int db = 0; db < 2; ++db)
#pragma unroll
            for (int i = 0; i < 16; ++i) yacc[db][i] *= corr;
          m_run = m_new;
        }
        // exp + pack to bf16 quads (pk[tb][4a+2*grp+pair], regs 4q4..4q4+3)
        unsigned pk[2][8];
        float ps = 0.f;
#pragma unroll
        for (int tb = 0; tb < 2; ++tb)
#pragma unroll
          for (int q4 = 0; q4 < 4; ++q4) {
            float p0 = exp2v(s[tb][4 * q4 + 0] - m_run);
            float p1 = exp2v(s[tb][4 * q4 + 1] - m_run);
            float p2 = exp2v(s[tb][4 * q4 + 2] - m_run);
            float p3 = exp2v(s[tb][4 * q4 + 3] - m_run);
            ps += ((p0 + p1) + (p2 + p3));
            pk[tb][2 * q4] = cvtpk(p0, p1);
            pk[tb][2 * q4 + 1] = cvtpk(p2, p3);
          }
        l_part += ps;

        // PV: per 16-k window kw: B-frag built with 2 shfl_xor(32) + selects
#pragma unroll
        for (int kw = 0; kw < 4; ++kw) {
          const int tb = kw >> 1, a = kw & 1;
          unsigned g00 = pk[tb][4 * a + 0], g01 = pk[tb][4 * a + 1];
          unsigned g10 = pk[tb][4 * a + 2], g11 = pk[tb][4 * a + 3];
          unsigned own0 = hi ? g10 : g00, own1 = hi ? g11 : g01;
          unsigned snd0 = hi ? g00 : g10, snd1 = hi ? g01 : g11;
          unsigned X0 = __shfl_xor(snd0, 32), X1 = __shfl_xor(snd1, 32);
          union { unsigned int u[4]; bf16x8 v; } pb;
          pb.u[0] = hi ? X0 : own0;
          pb.u[1] = hi ? X1 : own1;
          pb.u[2] = hi ? own0 : X0;
          pb.u[3] = hi ? own1 : X1;
          const int chv = ((2 * kw + hi) ^ l7) * 16;
          __builtin_amdgcn_s_setprio(1);
#pragma unroll
          for (int db = 0; db < 2; ++db) {
            const int row = 32 * db + q32;
            bf16x8 vf = *(const bf16x8*)(VsC + row * 128 + chv);
            yacc[db] = MFMA3216(vf, pb.v, yacc[db]);
          }
          __builtin_amdgcn_s_setprio(0);
        }
      }
      __builtin_amdgcn_s_barrier();  // readers done before next stage overwrite
    }

    float lt = l_part + __shfl_xor(l_part, 32);
    float inv = 1.f / lt;
    const int b = bh >> 4, hh = bh & 15;
    unsigned short* yrow = y_ws + (size_t)(b * 2048 + qcol) * 1024 + hh * 64;
#pragma unroll
    for (int db = 0; db < 2; ++db)
#pragma unroll
      for (int rg = 0; rg < 4; ++rg) {
        uint2 o;
        o.x = cvtpk(yacc[db][4 * rg + 0] * inv, yacc[db][4 * rg + 1] * inv);
        o.y = cvtpk(yacc[db][4 * rg + 2] * inv, yacc[db][4 * rg + 3] * inv);
        *(uint2*)(yrow + 32 * db + 8 * rg + 4 * hi) = o;
      }
  }
}

// ---------------------------------------------------------------------------
extern "C" void kernel_launch(void* const* d_in, const int* in_sizes, int n_in,
                              void* d_out, int out_size, void* d_ws, size_t ws_size,
                              hipStream_t stream) {
  const float* x = (const float*)d_in[0];      // (4, 2048, 1024)
  const float* Wqkv = (const float*)d_in[1];   // (1024, 3072)
  const float* Wproj = (const float*)d_in[2];  // (1024, 1024)
  float* out = (float*)d_out;                  // (4, 2048, 1024)
  char* ws = (char*)d_ws;

  unsigned short* x_bf = (unsigned short*)(ws);                    // 16 MiB
  unsigned short* wqkvT = (unsigned short*)(ws + 16777216);        // 6 MiB
  unsigned short* wprojT = (unsigned short*)(ws + 23068672);       // 2 MiB
  unsigned short* q_ws = (unsigned short*)(ws + 25165824);         // 16 MiB
  unsigned short* k_ws = (unsigned short*)(ws + 41943040);         // 16 MiB
  unsigned short* v_ws = (unsigned short*)(ws + 58720256);         // 16 MiB
  unsigned short* y_ws = (unsigned short*)(ws + 75497472);         // 16 MiB

  k_conv_x<<<8192, 256, 0, stream>>>(x, x_bf, 2097152);
  k_transpose<<<dim3(96, 32), 256, 0, stream>>>(Wqkv, wqkvT, 1024, 3072);
  k_transpose<<<dim3(32, 32), 256, 0, stream>>>(Wproj, wprojT, 1024, 1024);
  k_gemm<0><<<dim3(24, 64), 256, 0, stream>>>(x_bf, wqkvT, nullptr, q_ws, k_ws, v_ws, 8192, 3072);
  k_attn<<<512, 256, 0, stream>>>(q_ws, k_ws, v_ws, y_ws);
  k_gemm<1><<<dim3(8, 64), 256, 0, stream>>>(y_ws, wprojT, out, nullptr, nullptr, nullptr, 8192, 1024);
}

// Round 17
// 181.338 us; speedup vs baseline: 1.0359x; 1.0116x over previous
//
#include <hip/hip_runtime.h>
#include <cstdint>
#include <cstddef>

// ---------------------------------------------------------------------------
// MHA block: out = proj( causal_softmax( (xWq)(xWk)^T / 8 ) (xWv) )
// B=4, T=2048, C=1024, H=16, D=64.  All GEMM-shaped compute on bf16 MFMA.
// ---------------------------------------------------------------------------

typedef short bf16x8 __attribute__((ext_vector_type(8)));
typedef float f32x4 __attribute__((ext_vector_type(4)));
typedef float f32x16 __attribute__((ext_vector_type(16)));

#define MFMA32(a, b, c) __builtin_amdgcn_mfma_f32_16x16x32_bf16((a), (b), (c), 0, 0, 0)
#define MFMA3216(a, b, c) __builtin_amdgcn_mfma_f32_32x32x16_bf16((a), (b), (c), 0, 0, 0)

__device__ __forceinline__ unsigned short f2b(float f) {
  unsigned int x = __builtin_bit_cast(unsigned int, f);
  x += 0x7fffu + ((x >> 16) & 1u);
  return (unsigned short)(x >> 16);
}

__device__ __forceinline__ unsigned int pack2(float a, float b) {
  return (unsigned int)f2b(a) | ((unsigned int)f2b(b) << 16);
}

__device__ __forceinline__ unsigned int cvtpk(float a, float b) {
  unsigned int r;
  asm("v_cvt_pk_bf16_f32 %0, %1, %2" : "=v"(r) : "v"(a), "v"(b));
  return r;
}

__device__ __forceinline__ float exp2v(float x) {
  float r;
  asm("v_exp_f32 %0, %1" : "=v"(r) : "v"(x));
  return r;
}

__device__ __forceinline__ void gload16(const void* g, void* l) {
  __builtin_amdgcn_global_load_lds(
      (const __attribute__((address_space(1))) void*)g,
      (__attribute__((address_space(3))) void*)l, 16, 0, 0);
}

// ---------------------------------------------------------------------------
__global__ __launch_bounds__(256) void k_conv_x(const float* __restrict__ in,
                                                unsigned short* __restrict__ out, int n4) {
  int i = blockIdx.x * 256 + threadIdx.x;
  if (i >= n4) return;
  float4 v = reinterpret_cast<const float4*>(in)[i];
  ushort4 o;
  o.x = f2b(v.x); o.y = f2b(v.y); o.z = f2b(v.z); o.w = f2b(v.w);
  reinterpret_cast<ushort4*>(out)[i] = o;
}

// ---------------------------------------------------------------------------
__global__ __launch_bounds__(256) void k_transpose(const float* __restrict__ in,
                                                   unsigned short* __restrict__ out,
                                                   int R, int C) {
  __shared__ float tile[32][33];
  int c0 = blockIdx.x * 32, r0 = blockIdx.y * 32;
  int tx = threadIdx.x & 31, ty = threadIdx.x >> 5;
#pragma unroll
  for (int j = 0; j < 4; ++j)
    tile[ty + 8 * j][tx] = in[(size_t)(r0 + ty + 8 * j) * C + c0 + tx];
  __syncthreads();
#pragma unroll
  for (int j = 0; j < 4; ++j)
    out[(size_t)(c0 + ty + 8 * j) * R + r0 + tx] = f2b(tile[tx][ty + 8 * j]);
}

// ---------------------------------------------------------------------------
// bf16 GEMM (R14 mainloop: m97 + both-sides LDS XOR-swizzle, BK=64,
// conflict-free ds_reads).  128x128 tile, 4 waves, 64x64/wave.
// NEW (R17): __launch_bounds__(256, 5) — caps VGPR at ~102 so 5 blocks/CU
//   fit (LDS allows exactly 5 x 32KB); was VGPR-limited to 4.  +25% resident
//   waves for the inter-block overlap that hides the barrier drains.
// EPI=0: LDS-bounce epilogue -> q/k/v ws.  EPI=1: direct f32 out.
// ---------------------------------------------------------------------------
template <int EPI>
__global__ __launch_bounds__(256, 5) void k_gemm(const unsigned short* __restrict__ A,
                                                 const unsigned short* __restrict__ Bt,
                                                 float* __restrict__ outF,
                                                 unsigned short* __restrict__ q_ws,
                                                 unsigned short* __restrict__ k_ws,
                                                 unsigned short* __restrict__ v_ws,
                                                 int M, int N) {
  constexpr int K = 1024;
  __shared__ unsigned short smem[16384];  // As | Bs; epilogue reuses
  unsigned short* As = smem;
  unsigned short* Bs = smem + 8192;
  const int bn = blockIdx.x, bm = blockIdx.y;
  const int tid = threadIdx.x;
  const int w = tid >> 6, lane = tid & 63;
  const int wm = w >> 1, wn = w & 1;
  const int c = lane & 15, g = lane >> 4;
  const int cl8 = c & 7;

  f32x4 acc[4][4];
#pragma unroll
  for (int i = 0; i < 4; ++i)
#pragma unroll
    for (int j = 0; j < 4; ++j) acc[i][j] = (f32x4){0.f, 0.f, 0.f, 0.f};

  const int srow = 32 * w + (lane >> 3);
  const int scol = 8 * ((lane & 7) ^ (lane >> 3));
  const unsigned short* Ag = A + (size_t)(bm * 128 + srow) * K + scol;
  const unsigned short* Bg = Bt + (size_t)(bn * 128 + srow) * K + scol;
  char* AsB = (char*)As + w * 4096;
  char* BsB = (char*)Bs + w * 4096;

  for (int kt = 0; kt < K / 64; ++kt) {
    const int kb = kt * 64;
    __syncthreads();
#pragma unroll
    for (int i = 0; i < 4; ++i) {
      gload16(Ag + (size_t)(8 * i) * K + kb, AsB + i * 1024);
      gload16(Bg + (size_t)(8 * i) * K + kb, BsB + i * 1024);
    }
    asm volatile("s_waitcnt vmcnt(0)" ::: "memory");
    __syncthreads();
#pragma unroll
    for (int u = 0; u < 2; ++u) {
      bf16x8 af[4], bfr[4];
#pragma unroll
      for (int mf = 0; mf < 4; ++mf)
        af[mf] = *(const bf16x8*)((const char*)As + (wm * 64 + mf * 16 + c) * 128 +
                                  (((u * 4 + g) ^ cl8) * 16));
#pragma unroll
      for (int nf = 0; nf < 4; ++nf)
        bfr[nf] = *(const bf16x8*)((const char*)Bs + (wn * 64 + nf * 16 + c) * 128 +
                                   (((u * 4 + g) ^ cl8) * 16));
#pragma unroll
      for (int mf = 0; mf < 4; ++mf)
#pragma unroll
        for (int nf = 0; nf < 4; ++nf)
          acc[mf][nf] = MFMA32(af[mf], bfr[nf], acc[mf][nf]);
    }
  }

  const int rowb = bm * 128 + wm * 64;
  const int colb = bn * 128 + wn * 64;
  if (EPI == 1) {
#pragma unroll
    for (int mf = 0; mf < 4; ++mf)
#pragma unroll
      for (int nf = 0; nf < 4; ++nf)
#pragma unroll
        for (int r = 0; r < 4; ++r) {
          int row = rowb + mf * 16 + 4 * g + r;
          int col = colb + nf * 16 + c;
          outF[(size_t)row * N + col] = acc[mf][nf][r];
        }
  } else {
    const int sec = colb >> 10;
    const int hh = (colb & 1023) >> 6;
    const int b = rowb >> 11, t0 = rowb & 2047;
    unsigned short* Lw = smem + w * 4096;

    __syncthreads();
    if (sec < 2) {
      const float sc = (sec == 0) ? 0.125f * 1.4426950408889634f : 1.f;
#pragma unroll
      for (int mf = 0; mf < 4; ++mf)
#pragma unroll
        for (int nf = 0; nf < 4; ++nf)
#pragma unroll
          for (int r = 0; r < 4; ++r)
            Lw[(16 * mf + 4 * g + r) * 64 + 16 * nf + c] = f2b(acc[mf][nf][r] * sc);
    } else {
#pragma unroll
      for (int mf = 0; mf < 4; ++mf)
#pragma unroll
        for (int nf = 0; nf < 4; ++nf)
#pragma unroll
          for (int rr = 0; rr < 2; ++rr)
            *(unsigned int*)&Lw[(16 * nf + c) * 64 + 16 * mf + 4 * g + 2 * rr] =
                pack2(acc[mf][nf][2 * rr], acc[mf][nf][2 * rr + 1]);
    }
    asm volatile("s_waitcnt lgkmcnt(0)" ::: "memory");
    const int rw = lane >> 3, ch = lane & 7;
    const int chx = ch ^ rw;
    if (sec == 0) {
      unsigned short* dst = q_ws + ((size_t)(b * 16 + hh) * 2048 + t0) * 64;
#pragma unroll
      for (int i = 0; i < 8; ++i) {
        int tl = i * 8 + rw;
        *(bf16x8*)(dst + (size_t)tl * 64 + ch * 8) = *(const bf16x8*)&Lw[tl * 64 + ch * 8];
      }
    } else if (sec == 1) {
      unsigned short* dst = k_ws + ((size_t)(b * 16 + hh) * 2048 + t0) * 64;
#pragma unroll
      for (int i = 0; i < 8; ++i) {
        int tl = i * 8 + rw;
        *(bf16x8*)(dst + (size_t)tl * 64 + chx * 8) = *(const bf16x8*)&Lw[tl * 64 + ch * 8];
      }
    } else {
      unsigned short* dst = v_ws + (size_t)(b * 16 + hh) * 64 * 2048 + t0;
#pragma unroll
      for (int i = 0; i < 8; ++i) {
        int dl = i * 8 + rw;
        *(bf16x8*)(dst + (size_t)dl * 2048 + chx * 8) = *(const bf16x8*)&Lw[dl * 64 + ch * 8];
      }
    }
  }
}

// ---------------------------------------------------------------------------
// Flash attention, causal.  Exact R16 (best): 32x32x16 MFMA structure.
// 512 blocks x 256 threads (4 waves), 4 blocks/CU = 16 waves/CU.
// Wave owns 32 q-rows (col = lane&31); lane-local softmax + 1 shfl_xor(32);
// P->B-operand regroup with 2 shfl_xor(32)/kw; KVBLK=64 double-buffered,
// counted vmcnt(4), raw s_barrier.
// ---------------------------------------------------------------------------
__global__ __launch_bounds__(256, 4) void k_attn(const unsigned short* __restrict__ q_ws,
                                                 const unsigned short* __restrict__ k_ws,
                                                 const unsigned short* __restrict__ v_ws,
                                                 unsigned short* __restrict__ y_ws) {
  constexpr int T = 2048;
  __shared__ unsigned short Ks[2][64 * 64];
  __shared__ unsigned short Vs[2][64 * 64];
  const int f = blockIdx.x;
  const int f2 = (f & 7) * 64 + (f >> 3);
  const int bh = f2 >> 3;
  const int xi = f2 & 7;
  const int tid = threadIdx.x, w = tid >> 6, lane = tid & 63;
  const int q32 = lane & 31;  // q-col within wave tile; also K/V row index
  const int hi = lane >> 5;
  const int l7 = lane & 7;
  const size_t base = (size_t)bh * T * 64;
  const unsigned short* Kb = k_ws + base;
  const unsigned short* Vb = v_ws + base;
  const unsigned short* Qb = q_ws + base;

  const int srow = w * 16 + (lane >> 3);  // staging rows (2 instrs x 8 rows)
  const int sch = lane & 7;

#pragma unroll 1
  for (int ph = 0; ph < 2; ++ph) {
    const int q0 = (ph == 0 ? xi : 15 - xi) * 128;
    const int qb = q0 + 32 * w;
    const int qcol = qb + q32;
    const int n_kt = (q0 >> 6) + 2;
    bf16x8 qf[4];
#pragma unroll
    for (int ks = 0; ks < 4; ++ks)
      qf[ks] = *(const bf16x8*)(Qb + (size_t)qcol * 64 + 16 * ks + 8 * hi);

    f32x16 yacc[2];
#pragma unroll
    for (int db = 0; db < 2; ++db)
#pragma unroll
      for (int i = 0; i < 16; ++i) yacc[db][i] = 0.f;
    float m_run = -1e30f, l_part = 0.f;

    __syncthreads();  // prior phase fully done (drains all) before restaging
    gload16(Kb + (size_t)srow * 64 + sch * 8, (char*)&Ks[0][0] + w * 2048);
    gload16(Kb + (size_t)(srow + 8) * 64 + sch * 8, (char*)&Ks[0][0] + w * 2048 + 1024);
    gload16(Vb + (size_t)srow * T + sch * 8, (char*)&Vs[0][0] + w * 2048);
    gload16(Vb + (size_t)(srow + 8) * T + sch * 8, (char*)&Vs[0][0] + w * 2048 + 1024);

#pragma unroll 1
    for (int kt = 0; kt < n_kt; ++kt) {
      const int k0 = kt * 64;
      const int cur = kt & 1;
      if (kt + 1 < n_kt) {
        const int k0n = k0 + 64;
        char* KsW = (char*)&Ks[cur ^ 1][0] + w * 2048;
        char* VsW = (char*)&Vs[cur ^ 1][0] + w * 2048;
        gload16(Kb + (size_t)(k0n + srow) * 64 + sch * 8, KsW);
        gload16(Kb + (size_t)(k0n + srow + 8) * 64 + sch * 8, KsW + 1024);
        gload16(Vb + (size_t)srow * T + k0n + sch * 8, VsW);
        gload16(Vb + (size_t)(srow + 8) * T + k0n + sch * 8, VsW + 1024);
        asm volatile("s_waitcnt vmcnt(4)" ::: "memory");
      } else {
        asm volatile("s_waitcnt vmcnt(0)" ::: "memory");
      }
      __builtin_amdgcn_s_barrier();

      if (k0 <= qb + 31) {  // wave-uniform
        const char* KsC = (const char*)&Ks[cur][0];
        const char* VsC = (const char*)&Vs[cur][0];
        // QK^T: S^T[tk][q] per 32-row tk-block, 4 k-steps of 16 over D=64
        f32x16 s[2];
#pragma unroll
        for (int tb = 0; tb < 2; ++tb)
#pragma unroll
          for (int i = 0; i < 16; ++i) s[tb][i] = 0.f;
        __builtin_amdgcn_s_setprio(1);
#pragma unroll
        for (int ks = 0; ks < 4; ++ks) {
          const int chk = ((2 * ks + hi) ^ l7) * 16;
#pragma unroll
          for (int tb = 0; tb < 2; ++tb) {
            const int row = 32 * tb + q32;
            bf16x8 kf = *(const bf16x8*)(KsC + row * 128 + chk);
            s[tb] = MFMA3216(kf, qf[ks], s[tb]);
          }
        }
        __builtin_amdgcn_s_setprio(0);
        // causal mask (diagonal tiles only): tk = k0+32tb+(r&3)+8*(r>>2)+4hi
        if (k0 + 63 > qb) {
#pragma unroll
          for (int tb = 0; tb < 2; ++tb)
#pragma unroll
            for (int r = 0; r < 16; ++r) {
              int tk = k0 + 32 * tb + (r & 3) + 8 * (r >> 2) + 4 * hi;
              if (tk > qcol) s[tb][r] = -1e30f;
            }
        }
        // lane-local max over own 32 rows + cross-half combine
        float mx = s[0][0];
#pragma unroll
        for (int tb = 0; tb < 2; ++tb)
#pragma unroll
          for (int r = 0; r < 16; ++r) mx = fmaxf(mx, s[tb][r]);
        mx = fmaxf(mx, __shfl_xor(mx, 32));
        if (__any(mx > m_run + 11.5f)) {
          float m_new = fmaxf(m_run, mx);
          float corr = exp2v(m_run - m_new);
          l_part *= corr;
#pragma unroll
          for (int db = 0; db < 2; ++db)
#pragma unroll
            for (int i = 0; i < 16; ++i) yacc[db][i] *= corr;
          m_run = m_new;
        }
        // exp + pack to bf16 quads
        unsigned pk[2][8];
        float ps = 0.f;
#pragma unroll
        for (int tb = 0; tb < 2; ++tb)
#pragma unroll
          for (int q4 = 0; q4 < 4; ++q4) {
            float p0 = exp2v(s[tb][4 * q4 + 0] - m_run);
            float p1 = exp2v(s[tb][4 * q4 + 1] - m_run);
            float p2 = exp2v(s[tb][4 * q4 + 2] - m_run);
            float p3 = exp2v(s[tb][4 * q4 + 3] - m_run);
            ps += ((p0 + p1) + (p2 + p3));
            pk[tb][2 * q4] = cvtpk(p0, p1);
            pk[tb][2 * q4 + 1] = cvtpk(p2, p3);
          }
        l_part += ps;

        // PV: per 16-k window kw: B-frag built with 2 shfl_xor(32) + selects
#pragma unroll
        for (int kw = 0; kw < 4; ++kw) {
          const int tb = kw >> 1, a = kw & 1;
          unsigned g00 = pk[tb][4 * a + 0], g01 = pk[tb][4 * a + 1];
          unsigned g10 = pk[tb][4 * a + 2], g11 = pk[tb][4 * a + 3];
          unsigned own0 = hi ? g10 : g00, own1 = hi ? g11 : g01;
          unsigned snd0 = hi ? g00 : g10, snd1 = hi ? g01 : g11;
          unsigned X0 = __shfl_xor(snd0, 32), X1 = __shfl_xor(snd1, 32);
          union { unsigned int u[4]; bf16x8 v; } pb;
          pb.u[0] = hi ? X0 : own0;
          pb.u[1] = hi ? X1 : own1;
          pb.u[2] = hi ? own0 : X0;
          pb.u[3] = hi ? own1 : X1;
          const int chv = ((2 * kw + hi) ^ l7) * 16;
          __builtin_amdgcn_s_setprio(1);
#pragma unroll
          for (int db = 0; db < 2; ++db) {
            const int row = 32 * db + q32;
            bf16x8 vf = *(const bf16x8*)(VsC + row * 128 + chv);
            yacc[db] = MFMA3216(vf, pb.v, yacc[db]);
          }
          __builtin_amdgcn_s_setprio(0);
        }
      }
      __builtin_amdgcn_s_barrier();  // readers done before next stage overwrite
    }

    float lt = l_part + __shfl_xor(l_part, 32);
    float inv = 1.f / lt;
    const int b = bh >> 4, hh = bh & 15;
    unsigned short* yrow = y_ws + (size_t)(b * 2048 + qcol) * 1024 + hh * 64;
#pragma unroll
    for (int db = 0; db < 2; ++db)
#pragma unroll
      for (int rg = 0; rg < 4; ++rg) {
        uint2 o;
        o.x = cvtpk(yacc[db][4 * rg + 0] * inv, yacc[db][4 * rg + 1] * inv);
        o.y = cvtpk(yacc[db][4 * rg + 2] * inv, yacc[db][4 * rg + 3] * inv);
        *(uint2*)(yrow + 32 * db + 8 * rg + 4 * hi) = o;
      }
  }
}

// ---------------------------------------------------------------------------
extern "C" void kernel_launch(void* const* d_in, const int* in_sizes, int n_in,
                              void* d_out, int out_size, void* d_ws, size_t ws_size,
                              hipStream_t stream) {
  const float* x = (const float*)d_in[0];      // (4, 2048, 1024)
  const float* Wqkv = (const float*)d_in[1];   // (1024, 3072)
  const float* Wproj = (const float*)d_in[2];  // (1024, 1024)
  float* out = (float*)d_out;                  // (4, 2048, 1024)
  char* ws = (char*)d_ws;

  unsigned short* x_bf = (unsigned short*)(ws);                    // 16 MiB
  unsigned short* wqkvT = (unsigned short*)(ws + 16777216);        // 6 MiB
  unsigned short* wprojT = (unsigned short*)(ws + 23068672);       // 2 MiB
  unsigned short* q_ws = (unsigned short*)(ws + 25165824);         // 16 MiB
  unsigned short* k_ws = (unsigned short*)(ws + 41943040);         // 16 MiB
  unsigned short* v_ws = (unsigned short*)(ws + 58720256);         // 16 MiB
  unsigned short* y_ws = (unsigned short*)(ws + 75497472);         // 16 MiB

  k_conv_x<<<8192, 256, 0, stream>>>(x, x_bf, 2097152);
  k_transpose<<<dim3(96, 32), 256, 0, stream>>>(Wqkv, wqkvT, 1024, 3072);
  k_transpose<<<dim3(32, 32), 256, 0, stream>>>(Wproj, wprojT, 1024, 1024);
  k_gemm<0><<<dim3(24, 64), 256, 0, stream>>>(x_bf, wqkvT, nullptr, q_ws, k_ws, v_ws, 8192, 3072);
  k_attn<<<512, 256, 0, stream>>>(q_ws, k_ws, v_ws, y_ws);
  k_gemm<1><<<dim3(8, 64), 256, 0, stream>>>(y_ws, wprojT, out, nullptr, nullptr, nullptr, 8192, 1024);
}

// Round 18
// 172.856 us; speedup vs baseline: 1.0867x; 1.0491x over previous
//
#include <hip/hip_runtime.h>
#include <cstdint>
#include <cstddef>

// ---------------------------------------------------------------------------
// MHA block: out = proj( causal_softmax( (xWq)(xWk)^T / 8 ) (xWv) )
// B=4, T=2048, C=1024, H=16, D=64.  All GEMM-shaped compute on bf16 MFMA.
// ---------------------------------------------------------------------------

typedef short bf16x8 __attribute__((ext_vector_type(8)));
typedef float f32x4 __attribute__((ext_vector_type(4)));
typedef float f32x16 __attribute__((ext_vector_type(16)));

#define MFMA32(a, b, c) __builtin_amdgcn_mfma_f32_16x16x32_bf16((a), (b), (c), 0, 0, 0)
#define MFMA3216(a, b, c) __builtin_amdgcn_mfma_f32_32x32x16_bf16((a), (b), (c), 0, 0, 0)

__device__ __forceinline__ unsigned short f2b(float f) {
  unsigned int x = __builtin_bit_cast(unsigned int, f);
  x += 0x7fffu + ((x >> 16) & 1u);
  return (unsigned short)(x >> 16);
}

__device__ __forceinline__ unsigned int pack2(float a, float b) {
  return (unsigned int)f2b(a) | ((unsigned int)f2b(b) << 16);
}

__device__ __forceinline__ unsigned int cvtpk(float a, float b) {
  unsigned int r;
  asm("v_cvt_pk_bf16_f32 %0, %1, %2" : "=v"(r) : "v"(a), "v"(b));
  return r;
}

__device__ __forceinline__ float exp2v(float x) {
  float r;
  asm("v_exp_f32 %0, %1" : "=v"(r) : "v"(x));
  return r;
}

__device__ __forceinline__ void gload16(const void* g, void* l) {
  __builtin_amdgcn_global_load_lds(
      (const __attribute__((address_space(1))) void*)g,
      (__attribute__((address_space(3))) void*)l, 16, 0, 0);
}

// ---------------------------------------------------------------------------
__global__ __launch_bounds__(256) void k_conv_x(const float* __restrict__ in,
                                                unsigned short* __restrict__ out, int n4) {
  int i = blockIdx.x * 256 + threadIdx.x;
  if (i >= n4) return;
  float4 v = reinterpret_cast<const float4*>(in)[i];
  ushort4 o;
  o.x = f2b(v.x); o.y = f2b(v.y); o.z = f2b(v.z); o.w = f2b(v.w);
  reinterpret_cast<ushort4*>(out)[i] = o;
}

// ---------------------------------------------------------------------------
__global__ __launch_bounds__(256) void k_transpose(const float* __restrict__ in,
                                                   unsigned short* __restrict__ out,
                                                   int R, int C) {
  __shared__ float tile[32][33];
  int c0 = blockIdx.x * 32, r0 = blockIdx.y * 32;
  int tx = threadIdx.x & 31, ty = threadIdx.x >> 5;
#pragma unroll
  for (int j = 0; j < 4; ++j)
    tile[ty + 8 * j][tx] = in[(size_t)(r0 + ty + 8 * j) * C + c0 + tx];
  __syncthreads();
#pragma unroll
  for (int j = 0; j < 4; ++j)
    out[(size_t)(c0 + ty + 8 * j) * R + r0 + tx] = f2b(tile[tx][ty + 8 * j]);
}

// ---------------------------------------------------------------------------
// bf16 GEMM (exact R17: m97 mainloop + both-sides LDS XOR-swizzle, BK=64,
// launch_bounds(256,5) -> 5 blocks/CU).  128x128 tile, 4 waves, 64x64/wave.
// EPI=0: LDS-bounce epilogue -> q/k/v ws.  EPI=1: direct f32 out.
// ---------------------------------------------------------------------------
template <int EPI>
__global__ __launch_bounds__(256, 5) void k_gemm(const unsigned short* __restrict__ A,
                                                 const unsigned short* __restrict__ Bt,
                                                 float* __restrict__ outF,
                                                 unsigned short* __restrict__ q_ws,
                                                 unsigned short* __restrict__ k_ws,
                                                 unsigned short* __restrict__ v_ws,
                                                 int M, int N) {
  constexpr int K = 1024;
  __shared__ unsigned short smem[16384];  // As | Bs; epilogue reuses
  unsigned short* As = smem;
  unsigned short* Bs = smem + 8192;
  const int bn = blockIdx.x, bm = blockIdx.y;
  const int tid = threadIdx.x;
  const int w = tid >> 6, lane = tid & 63;
  const int wm = w >> 1, wn = w & 1;
  const int c = lane & 15, g = lane >> 4;
  const int cl8 = c & 7;

  f32x4 acc[4][4];
#pragma unroll
  for (int i = 0; i < 4; ++i)
#pragma unroll
    for (int j = 0; j < 4; ++j) acc[i][j] = (f32x4){0.f, 0.f, 0.f, 0.f};

  const int srow = 32 * w + (lane >> 3);
  const int scol = 8 * ((lane & 7) ^ (lane >> 3));
  const unsigned short* Ag = A + (size_t)(bm * 128 + srow) * K + scol;
  const unsigned short* Bg = Bt + (size_t)(bn * 128 + srow) * K + scol;
  char* AsB = (char*)As + w * 4096;
  char* BsB = (char*)Bs + w * 4096;

  for (int kt = 0; kt < K / 64; ++kt) {
    const int kb = kt * 64;
    __syncthreads();
#pragma unroll
    for (int i = 0; i < 4; ++i) {
      gload16(Ag + (size_t)(8 * i) * K + kb, AsB + i * 1024);
      gload16(Bg + (size_t)(8 * i) * K + kb, BsB + i * 1024);
    }
    asm volatile("s_waitcnt vmcnt(0)" ::: "memory");
    __syncthreads();
#pragma unroll
    for (int u = 0; u < 2; ++u) {
      bf16x8 af[4], bfr[4];
#pragma unroll
      for (int mf = 0; mf < 4; ++mf)
        af[mf] = *(const bf16x8*)((const char*)As + (wm * 64 + mf * 16 + c) * 128 +
                                  (((u * 4 + g) ^ cl8) * 16));
#pragma unroll
      for (int nf = 0; nf < 4; ++nf)
        bfr[nf] = *(const bf16x8*)((const char*)Bs + (wn * 64 + nf * 16 + c) * 128 +
                                   (((u * 4 + g) ^ cl8) * 16));
#pragma unroll
      for (int mf = 0; mf < 4; ++mf)
#pragma unroll
        for (int nf = 0; nf < 4; ++nf)
          acc[mf][nf] = MFMA32(af[mf], bfr[nf], acc[mf][nf]);
    }
  }

  const int rowb = bm * 128 + wm * 64;
  const int colb = bn * 128 + wn * 64;
  if (EPI == 1) {
#pragma unroll
    for (int mf = 0; mf < 4; ++mf)
#pragma unroll
      for (int nf = 0; nf < 4; ++nf)
#pragma unroll
        for (int r = 0; r < 4; ++r) {
          int row = rowb + mf * 16 + 4 * g + r;
          int col = colb + nf * 16 + c;
          outF[(size_t)row * N + col] = acc[mf][nf][r];
        }
  } else {
    const int sec = colb >> 10;
    const int hh = (colb & 1023) >> 6;
    const int b = rowb >> 11, t0 = rowb & 2047;
    unsigned short* Lw = smem + w * 4096;

    __syncthreads();
    if (sec < 2) {
      const float sc = (sec == 0) ? 0.125f * 1.4426950408889634f : 1.f;
#pragma unroll
      for (int mf = 0; mf < 4; ++mf)
#pragma unroll
        for (int nf = 0; nf < 4; ++nf)
#pragma unroll
          for (int r = 0; r < 4; ++r)
            Lw[(16 * mf + 4 * g + r) * 64 + 16 * nf + c] = f2b(acc[mf][nf][r] * sc);
    } else {
#pragma unroll
      for (int mf = 0; mf < 4; ++mf)
#pragma unroll
        for (int nf = 0; nf < 4; ++nf)
#pragma unroll
          for (int rr = 0; rr < 2; ++rr)
            *(unsigned int*)&Lw[(16 * nf + c) * 64 + 16 * mf + 4 * g + 2 * rr] =
                pack2(acc[mf][nf][2 * rr], acc[mf][nf][2 * rr + 1]);
    }
    asm volatile("s_waitcnt lgkmcnt(0)" ::: "memory");
    const int rw = lane >> 3, ch = lane & 7;
    const int chx = ch ^ rw;
    if (sec == 0) {
      unsigned short* dst = q_ws + ((size_t)(b * 16 + hh) * 2048 + t0) * 64;
#pragma unroll
      for (int i = 0; i < 8; ++i) {
        int tl = i * 8 + rw;
        *(bf16x8*)(dst + (size_t)tl * 64 + ch * 8) = *(const bf16x8*)&Lw[tl * 64 + ch * 8];
      }
    } else if (sec == 1) {
      unsigned short* dst = k_ws + ((size_t)(b * 16 + hh) * 2048 + t0) * 64;
#pragma unroll
      for (int i = 0; i < 8; ++i) {
        int tl = i * 8 + rw;
        *(bf16x8*)(dst + (size_t)tl * 64 + chx * 8) = *(const bf16x8*)&Lw[tl * 64 + ch * 8];
      }
    } else {
      unsigned short* dst = v_ws + (size_t)(b * 16 + hh) * 64 * 2048 + t0;
#pragma unroll
      for (int i = 0; i < 8; ++i) {
        int dl = i * 8 + rw;
        *(bf16x8*)(dst + (size_t)dl * 2048 + chx * 8) = *(const bf16x8*)&Lw[dl * 64 + ch * 8];
      }
    }
  }
}

// ---------------------------------------------------------------------------
// Flash attention, causal.  R16 32x32x16 compute, NEW (R18) scheduling:
// 1024 blocks x 256 thr (4 waves), ONE 128-row q-tile per block ->
// ~4 blocks/CU resident (16 waves/CU, was 8).  Causal imbalance handled by
// LONGEST-FIRST dispatch (xi descending within XCD chunk) + 4x oversubscribe
// refill; shortest blocks land last = clean tail.  8 bh planes/XCD (L2-fit).
// KVBLK=64 double-buffered, counted vmcnt(4), raw s_barrier.
// ---------------------------------------------------------------------------
__global__ __launch_bounds__(256, 4) void k_attn(const unsigned short* __restrict__ q_ws,
                                                 const unsigned short* __restrict__ k_ws,
                                                 const unsigned short* __restrict__ v_ws,
                                                 unsigned short* __restrict__ y_ws) {
  constexpr int T = 2048;
  __shared__ unsigned short Ks[2][64 * 64];
  __shared__ unsigned short Vs[2][64 * 64];
  // f&7 -> XCD chunk; within chunk: 8 bh planes, xi DESCENDING (longest first)
  const int f = blockIdx.x;
  const int r = f >> 3;
  const int bh = (f & 7) * 8 + (r & 7);
  const int xi = 15 - (r >> 3);
  const int tid = threadIdx.x, w = tid >> 6, lane = tid & 63;
  const int q32 = lane & 31;
  const int hi = lane >> 5;
  const int l7 = lane & 7;
  const size_t base = (size_t)bh * T * 64;
  const unsigned short* Kb = k_ws + base;
  const unsigned short* Vb = v_ws + base;
  const unsigned short* Qb = q_ws + base;

  const int srow = w * 16 + (lane >> 3);
  const int sch = lane & 7;

  const int q0 = xi * 128;
  const int qb = q0 + 32 * w;
  const int qcol = qb + q32;
  const int n_kt = (q0 >> 6) + 2;
  bf16x8 qf[4];
#pragma unroll
  for (int ks = 0; ks < 4; ++ks)
    qf[ks] = *(const bf16x8*)(Qb + (size_t)qcol * 64 + 16 * ks + 8 * hi);

  f32x16 yacc[2];
#pragma unroll
  for (int db = 0; db < 2; ++db)
#pragma unroll
    for (int i = 0; i < 16; ++i) yacc[db][i] = 0.f;
  float m_run = -1e30f, l_part = 0.f;

  // prologue: stage kt=0 into buf 0
  gload16(Kb + (size_t)srow * 64 + sch * 8, (char*)&Ks[0][0] + w * 2048);
  gload16(Kb + (size_t)(srow + 8) * 64 + sch * 8, (char*)&Ks[0][0] + w * 2048 + 1024);
  gload16(Vb + (size_t)srow * T + sch * 8, (char*)&Vs[0][0] + w * 2048);
  gload16(Vb + (size_t)(srow + 8) * T + sch * 8, (char*)&Vs[0][0] + w * 2048 + 1024);

#pragma unroll 1
  for (int kt = 0; kt < n_kt; ++kt) {
    const int k0 = kt * 64;
    const int cur = kt & 1;
    if (kt + 1 < n_kt) {
      const int k0n = k0 + 64;
      char* KsW = (char*)&Ks[cur ^ 1][0] + w * 2048;
      char* VsW = (char*)&Vs[cur ^ 1][0] + w * 2048;
      gload16(Kb + (size_t)(k0n + srow) * 64 + sch * 8, KsW);
      gload16(Kb + (size_t)(k0n + srow + 8) * 64 + sch * 8, KsW + 1024);
      gload16(Vb + (size_t)srow * T + k0n + sch * 8, VsW);
      gload16(Vb + (size_t)(srow + 8) * T + k0n + sch * 8, VsW + 1024);
      asm volatile("s_waitcnt vmcnt(4)" ::: "memory");
    } else {
      asm volatile("s_waitcnt vmcnt(0)" ::: "memory");
    }
    __builtin_amdgcn_s_barrier();

    if (k0 <= qb + 31) {  // wave-uniform
      const char* KsC = (const char*)&Ks[cur][0];
      const char* VsC = (const char*)&Vs[cur][0];
      f32x16 s[2];
#pragma unroll
      for (int tb = 0; tb < 2; ++tb)
#pragma unroll
        for (int i = 0; i < 16; ++i) s[tb][i] = 0.f;
      __builtin_amdgcn_s_setprio(1);
#pragma unroll
      for (int ks = 0; ks < 4; ++ks) {
        const int chk = ((2 * ks + hi) ^ l7) * 16;
#pragma unroll
        for (int tb = 0; tb < 2; ++tb) {
          const int row = 32 * tb + q32;
          bf16x8 kf = *(const bf16x8*)(KsC + row * 128 + chk);
          s[tb] = MFMA3216(kf, qf[ks], s[tb]);
        }
      }
      __builtin_amdgcn_s_setprio(0);
      if (k0 + 63 > qb) {  // causal mask: tk = k0+32tb+(r&3)+8*(r>>2)+4hi
#pragma unroll
        for (int tb = 0; tb < 2; ++tb)
#pragma unroll
          for (int rr = 0; rr < 16; ++rr) {
            int tk = k0 + 32 * tb + (rr & 3) + 8 * (rr >> 2) + 4 * hi;
            if (tk > qcol) s[tb][rr] = -1e30f;
          }
      }
      float mx = s[0][0];
#pragma unroll
      for (int tb = 0; tb < 2; ++tb)
#pragma unroll
        for (int rr = 0; rr < 16; ++rr) mx = fmaxf(mx, s[tb][rr]);
      mx = fmaxf(mx, __shfl_xor(mx, 32));
      if (__any(mx > m_run + 11.5f)) {
        float m_new = fmaxf(m_run, mx);
        float corr = exp2v(m_run - m_new);
        l_part *= corr;
#pragma unroll
        for (int db = 0; db < 2; ++db)
#pragma unroll
          for (int i = 0; i < 16; ++i) yacc[db][i] *= corr;
        m_run = m_new;
      }
      unsigned pk[2][8];
      float ps = 0.f;
#pragma unroll
      for (int tb = 0; tb < 2; ++tb)
#pragma unroll
        for (int q4 = 0; q4 < 4; ++q4) {
          float p0 = exp2v(s[tb][4 * q4 + 0] - m_run);
          float p1 = exp2v(s[tb][4 * q4 + 1] - m_run);
          float p2 = exp2v(s[tb][4 * q4 + 2] - m_run);
          float p3 = exp2v(s[tb][4 * q4 + 3] - m_run);
          ps += ((p0 + p1) + (p2 + p3));
          pk[tb][2 * q4] = cvtpk(p0, p1);
          pk[tb][2 * q4 + 1] = cvtpk(p2, p3);
        }
      l_part += ps;

#pragma unroll
      for (int kw = 0; kw < 4; ++kw) {
        const int tb = kw >> 1, a = kw & 1;
        unsigned g00 = pk[tb][4 * a + 0], g01 = pk[tb][4 * a + 1];
        unsigned g10 = pk[tb][4 * a + 2], g11 = pk[tb][4 * a + 3];
        unsigned own0 = hi ? g10 : g00, own1 = hi ? g11 : g01;
        unsigned snd0 = hi ? g00 : g10, snd1 = hi ? g01 : g11;
        unsigned X0 = __shfl_xor(snd0, 32), X1 = __shfl_xor(snd1, 32);
        union { unsigned int u[4]; bf16x8 v; } pb;
        pb.u[0] = hi ? X0 : own0;
        pb.u[1] = hi ? X1 : own1;
        pb.u[2] = hi ? own0 : X0;
        pb.u[3] = hi ? own1 : X1;
        const int chv = ((2 * kw + hi) ^ l7) * 16;
        __builtin_amdgcn_s_setprio(1);
#pragma unroll
        for (int db = 0; db < 2; ++db) {
          const int row = 32 * db + q32;
          bf16x8 vf = *(const bf16x8*)(VsC + row * 128 + chv);
          yacc[db] = MFMA3216(vf, pb.v, yacc[db]);
        }
        __builtin_amdgcn_s_setprio(0);
      }
    }
    __builtin_amdgcn_s_barrier();
  }

  float lt = l_part + __shfl_xor(l_part, 32);
  float inv = 1.f / lt;
  const int b = bh >> 4, hh = bh & 15;
  unsigned short* yrow = y_ws + (size_t)(b * 2048 + qcol) * 1024 + hh * 64;
#pragma unroll
  for (int db = 0; db < 2; ++db)
#pragma unroll
    for (int rg = 0; rg < 4; ++rg) {
      uint2 o;
      o.x = cvtpk(yacc[db][4 * rg + 0] * inv, yacc[db][4 * rg + 1] * inv);
      o.y = cvtpk(yacc[db][4 * rg + 2] * inv, yacc[db][4 * rg + 3] * inv);
      *(uint2*)(yrow + 32 * db + 8 * rg + 4 * hi) = o;
    }
}

// ---------------------------------------------------------------------------
extern "C" void kernel_launch(void* const* d_in, const int* in_sizes, int n_in,
                              void* d_out, int out_size, void* d_ws, size_t ws_size,
                              hipStream_t stream) {
  const float* x = (const float*)d_in[0];      // (4, 2048, 1024)
  const float* Wqkv = (const float*)d_in[1];   // (1024, 3072)
  const float* Wproj = (const float*)d_in[2];  // (1024, 1024)
  float* out = (float*)d_out;                  // (4, 2048, 1024)
  char* ws = (char*)d_ws;

  unsigned short* x_bf = (unsigned short*)(ws);                    // 16 MiB
  unsigned short* wqkvT = (unsigned short*)(ws + 16777216);        // 6 MiB
  unsigned short* wprojT = (unsigned short*)(ws + 23068672);       // 2 MiB
  unsigned short* q_ws = (unsigned short*)(ws + 25165824);         // 16 MiB
  unsigned short* k_ws = (unsigned short*)(ws + 41943040);         // 16 MiB
  unsigned short* v_ws = (unsigned short*)(ws + 58720256);         // 16 MiB
  unsigned short* y_ws = (unsigned short*)(ws + 75497472);         // 16 MiB

  k_conv_x<<<8192, 256, 0, stream>>>(x, x_bf, 2097152);
  k_transpose<<<dim3(96, 32), 256, 0, stream>>>(Wqkv, wqkvT, 1024, 3072);
  k_transpose<<<dim3(32, 32), 256, 0, stream>>>(Wproj, wprojT, 1024, 1024);
  k_gemm<0><<<dim3(24, 64), 256, 0, stream>>>(x_bf, wqkvT, nullptr, q_ws, k_ws, v_ws, 8192, 3072);
  k_attn<<<1024, 256, 0, stream>>>(q_ws, k_ws, v_ws, y_ws);
  k_gemm<1><<<dim3(8, 64), 256, 0, stream>>>(y_ws, wprojT, out, nullptr, nullptr, nullptr, 8192, 1024);
}